// Round 2
// baseline (20822.838 us; speedup 1.0000x reference)
//
#include <hip/hip_runtime.h>
#include <stdint.h>
#include <stdio.h>

#define T_ 10
#define B_ 16
#define S_ 200
#define D_ 768
#define H_ 300
#define NC_ 4
#define M_ (S_ * B_)   /* 3200 rows per t */
#define K5_ (5 * D_)   /* 3840 */
#define N2_ 2400       /* 2 dirs * 4H */
#define G4_ 1200       /* 4H */

typedef unsigned short u16;
typedef unsigned int u32;
typedef __attribute__((ext_vector_type(8))) short short8;
typedef __attribute__((ext_vector_type(4))) float float4v;

static __device__ __forceinline__ u16 f2bf(float x) {
  union { float f; u32 u; } v; v.f = x;
  u32 u = v.u;
  u32 r = (u + 0x7FFFu + ((u >> 16) & 1u)) >> 16;
  return (u16)r;
}

static __device__ __forceinline__ void async16(const void* g, void* l) {
  __builtin_amdgcn_global_load_lds((const __attribute__((address_space(1))) u32*)g,
                                   (__attribute__((address_space(3))) u32*)l, 16, 0, 0);
}

static __device__ __forceinline__ float sigmoid_f(float x) {
  return 1.f / (1.f + __expf(-x));
}
static __device__ __forceinline__ float tanh_f(float x) {
  float e = __expf(2.f * x);
  return 1.f - 2.f / (e + 1.f);   // safe at e=inf -> 1, e=0 -> -1
}

// ---------------------------------------------------------------------------
// K0a: build S0 = bf16(seq), SA = a .* seq, SB = b .* seq  (layout [t][s][b][768])
//      plus before-state SA0/SB0 (t=0 before-state weights on seq[0])
// ---------------------------------------------------------------------------
__global__ void k_prep_s(const float* __restrict__ seq,
                         const float* __restrict__ sp, const float* __restrict__ ep,
                         const float* __restrict__ cp,
                         const float* __restrict__ bsp, const float* __restrict__ bep,
                         const float* __restrict__ bcp,
                         const float* __restrict__ um, const float* __restrict__ nm,
                         const float* __restrict__ am,
                         u16* __restrict__ s0, u16* __restrict__ sa, u16* __restrict__ sb,
                         u16* __restrict__ sa0, u16* __restrict__ sb0) {
  int bid = blockIdx.x;
  int tid = threadIdx.x;  // 256
  if (bid < T_ * M_) {
    int t = bid / M_;
    int r = bid % M_;
    int s = r >> 4, b = r & 15;
    float c0 = cp[(t * B_ + b) * NC_ + 0];
    float c1 = cp[(t * B_ + b) * NC_ + 1];
    float c2 = cp[(t * B_ + b) * NC_ + 2];
    int mi = (b * T_ + t) * S_ + s;
    float w = am[mi] * c0 + um[mi] * c1 + nm[mi] * c2;
    float aw = sp[(t * B_ + b) * S_ + s] * w;
    float bw = ep[(t * B_ + b) * S_ + s] * w;
    const float* x = seq + ((size_t)(t * B_ + b) * S_ + s) * D_;
    size_t ob = (size_t)bid * D_;
    for (int d = tid; d < D_; d += 256) {
      float xv = x[d];
      s0[ob + d] = f2bf(xv);
      sa[ob + d] = f2bf(aw * xv);
      sb[ob + d] = f2bf(bw * xv);
    }
  } else {
    int r = bid - T_ * M_;
    int s = r >> 4, b = r & 15;
    float c0 = bcp[b * NC_ + 0], c1 = bcp[b * NC_ + 1], c2 = bcp[b * NC_ + 2];
    int mi = (b * T_ + 0) * S_ + s;
    float w = am[mi] * c0 + um[mi] * c1 + nm[mi] * c2;
    float aw = bsp[b * S_ + s] * w;
    float bw = bep[b * S_ + s] * w;
    const float* x = seq + ((size_t)b * S_ + s) * D_;
    size_t ob = (size_t)r * D_;
    for (int d = tid; d < D_; d += 256) {
      float xv = x[d];
      sa0[ob + d] = f2bf(aw * xv);
      sb0[ob + d] = f2bf(bw * xv);
    }
  }
}

// ---------------------------------------------------------------------------
// K0b: Wcat bf16 [2400][3840], Whh padded bf16 [2][1200][320], bias=bih+bhh,
//      d_out seeded with bcls, flags + hx zeroed
// ---------------------------------------------------------------------------
__global__ void k_prep_w(const float* __restrict__ wf, const float* __restrict__ wb,
                         const float* __restrict__ whf, const float* __restrict__ whb,
                         const float* __restrict__ bihf, const float* __restrict__ bhhf,
                         const float* __restrict__ bihb, const float* __restrict__ bhhb,
                         const float* __restrict__ bcls,
                         u16* __restrict__ wcat, u16* __restrict__ whh,
                         float* __restrict__ bias, float* __restrict__ outp,
                         int* __restrict__ flags, u16* __restrict__ hx) {
  int bid = blockIdx.x, tid = threadIdx.x;
  if (bid < N2_) {
    const float* src = bid < G4_ ? wf + (size_t)bid * K5_ : wb + (size_t)(bid - G4_) * K5_;
    u16* dst = wcat + (size_t)bid * K5_;
    for (int k = tid; k < K5_; k += 256) dst[k] = f2bf(src[k]);
  } else if (bid < N2_ + 2 * G4_) {
    int r = bid - N2_;
    int dir = r / G4_, n = r % G4_;
    const float* src = (dir ? whb : whf) + (size_t)n * H_;
    u16* dst = whh + (size_t)(dir * G4_ + n) * 320;
    for (int k = tid; k < 320; k += 256) dst[k] = (k < H_) ? f2bf(src[k]) : (u16)0;
  } else {
    for (int i = tid; i < 2 * G4_; i += 256) {
      int dir = i / G4_, n = i % G4_;
      bias[i] = dir ? (bihb[n] + bhhb[n]) : (bihf[n] + bhhf[n]);
    }
    for (int i = tid; i < T_ * B_ * NC_; i += 256) outp[i] = bcls[i & 3];
    for (int i = tid; i < 16; i += 256) flags[i] = 0;
    for (int i = tid; i < 2 * 2 * B_ * 320; i += 256) hx[i] = 0;
  }
}

// ---------------------------------------------------------------------------
// K1: z[s][b][2400] = rnn_in(t) @ [Wih_f;Wih_b]^T  (bf16 MFMA, fp32 out)
//     A source per 768-K-block: S0(t) / SA(t) / SB(t) / SA(t-1) / SB(t-1)
//     Writes the single-t Z slot.
// ---------------------------------------------------------------------------
__global__ __launch_bounds__(256, 3) void k_gemm(
    const u16* __restrict__ s0, const u16* __restrict__ sa, const u16* __restrict__ sb,
    const u16* __restrict__ sa0, const u16* __restrict__ sb0,
    const u16* __restrict__ wcat, float* __restrict__ z, int t) {
  __shared__ __align__(16) u16 As[128 * 32];
  __shared__ __align__(16) u16 Bs[128 * 32];
  int m0 = blockIdx.x * 128;
  int n0 = blockIdx.y * 128;
  int tid = threadIdx.x;
  int lane = tid & 63, wv = tid >> 6;
  int wm = wv & 1, wn = wv >> 1;

  const u16* ap[5];
  ap[0] = s0 + (size_t)t * M_ * D_;
  ap[1] = sa + (size_t)t * M_ * D_;
  ap[2] = sb + (size_t)t * M_ * D_;
  ap[3] = t ? sa + (size_t)(t - 1) * M_ * D_ : sa0;
  ap[4] = t ? sb + (size_t)(t - 1) * M_ * D_ : sb0;

  float4v acc[4][4];
#pragma unroll
  for (int i = 0; i < 4; i++)
#pragma unroll
    for (int j = 0; j < 4; j++) acc[i][j] = (float4v){0.f, 0.f, 0.f, 0.f};

  int rowA = tid >> 2;   // 0..63
  int seg = tid & 3;

  for (int which = 0; which < 5; ++which) {
    const u16* ab = which == 0 ? ap[0] : which == 1 ? ap[1] : which == 2 ? ap[2]
                    : which == 3 ? ap[3] : ap[4];
    for (int kk = 0; kk < 24; ++kk) {
      int kof = kk * 32;
#pragma unroll
      for (int j = 0; j < 2; ++j) {
        int row = j * 64 + rowA;
        const u16* g = ab + (size_t)(m0 + row) * D_ + kof + seg * 8;
        async16(g, As + wv * 512 + j * 2048);
      }
#pragma unroll
      for (int j = 0; j < 2; ++j) {
        int row = j * 64 + rowA;
        int nr = n0 + row;
        if (nr > N2_ - 1) nr = N2_ - 1;
        const u16* g = wcat + (size_t)nr * K5_ + which * D_ + kof + seg * 8;
        async16(g, Bs + wv * 512 + j * 2048);
      }
      __syncthreads();
      short8 af[4], bf[4];
#pragma unroll
      for (int i = 0; i < 4; i++) {
        af[i] = *(const short8*)&As[(wm * 64 + i * 16 + (lane & 15)) * 32 + (lane >> 4) * 8];
        bf[i] = *(const short8*)&Bs[(wn * 64 + i * 16 + (lane & 15)) * 32 + (lane >> 4) * 8];
      }
#pragma unroll
      for (int i = 0; i < 4; i++)
#pragma unroll
        for (int j = 0; j < 4; j++)
          acc[i][j] = __builtin_amdgcn_mfma_f32_16x16x32_bf16(af[i], bf[j], acc[i][j], 0, 0, 0);
      __syncthreads();
    }
  }
#pragma unroll
  for (int i = 0; i < 4; i++) {
    int m = m0 + wm * 64 + i * 16 + (lane >> 4) * 4;
#pragma unroll
    for (int j = 0; j < 4; j++) {
      int n = n0 + wn * 64 + j * 16 + (lane & 15);
      if (n < N2_) {
#pragma unroll
        for (int r = 0; r < 4; r++) z[(size_t)(m + r) * N2_ + n] = acc[i][j][r];
      }
    }
  }
}

// ---------------------------------------------------------------------------
// K2: persistent bidirectional LSTM + fused classifier, one t per launch.
// Grid = 10 blocks x 1024 thr -> (dir = b/5, w = b%5). Each wg owns u-slice
// [64w, 64w+64) of H(padded 320); Whh slice lives in registers as MFMA
// B-fragments. Per step: exchange h via global ring (depth 2) with
// release/acquire flag sync across the 5 wgs of a direction. c carry in CST.
// ---------------------------------------------------------------------------
__global__ __launch_bounds__(1024, 4) void k_lstm(
    const float* __restrict__ z, const u16* __restrict__ whh,
    const float* __restrict__ bias, const float* __restrict__ wcls,
    u16* __restrict__ hx, int* __restrict__ flags, float* __restrict__ outp,
    float* __restrict__ cst, int t) {
  __shared__ __align__(16) u16 h_lds[16 * 328];
  __shared__ __align__(16) float smem[4160];  // zbuf [4][16][65] / cls-reduce [16][64][4]

  int wgid = blockIdx.x;
  int dir = wgid / 5;
  int w = wgid % 5;
  int tid = threadIdx.x;
  int lane = tid & 63, wv = tid >> 6;
  int gate = wv >> 2, q = wv & 3;

  // persistent Whh B-fragments: wave covers cols n = gate*300 + w*64 + q*16 + (lane&15)
  short8 bfr[10];
  {
    int col = lane & 15;
    int u = w * 64 + q * 16 + col;
    int krow = (lane >> 4) * 8;
    if (u < H_) {
      const u16* base = whh + (size_t)(dir * G4_ + gate * H_ + u) * 320 + krow;
#pragma unroll
      for (int kk = 0; kk < 10; ++kk) bfr[kk] = *(const short8*)(base + kk * 32);
    } else {
#pragma unroll
      for (int kk = 0; kk < 10; ++kk) bfr[kk] = (short8){0, 0, 0, 0, 0, 0, 0, 0};
    }
  }

  // thread view for gate/classifier phase
  int b = tid >> 6;
  int u_loc = tid & 63;
  int u_glob = w * 64 + u_loc;
  bool active = u_glob < H_;
  float bias_r[4];
#pragma unroll
  for (int g = 0; g < 4; ++g)
    bias_r[g] = active ? bias[dir * G4_ + g * H_ + u_glob] : 0.f;

  float c_state = t > 0 ? cst[wgid * 1024 + tid] : 0.f;
  float clsacc[4] = {0.f, 0.f, 0.f, 0.f};

  for (int i = tid; i < 16 * 328; i += 1024) h_lds[i] = 0;
  __syncthreads();

  int* myflags = flags + dir * 8;
  const float* zd = z + dir * G4_;

  for (int s_mod = 0; s_mod < S_; ++s_mod) {
    int g = t * S_ + s_mod;
    int s_in = dir ? (S_ - 1 - s_mod) : s_mod;

    // prefetch (independent of sync): z input row + Wcls column
    float z_in[4] = {0.f, 0.f, 0.f, 0.f}, wc[4] = {0.f, 0.f, 0.f, 0.f};
    if (active) {
      const float* zr = zd + ((size_t)(s_in * B_ + b)) * N2_;
      int ycol = s_in * 600 + dir * H_ + u_glob;
#pragma unroll
      for (int gg = 0; gg < 4; ++gg) z_in[gg] = zr[gg * H_ + u_glob];
#pragma unroll
      for (int n = 0; n < 4; ++n) wc[n] = wcls[(size_t)n * (S_ * 600) + ycol];
    }

    if (g > 0) {
      if (wv == 0) {
        int v = INT32_MAX;
        int tries = 0;
        do {
          if (lane < 5)
            v = __hip_atomic_load(&myflags[lane], __ATOMIC_ACQUIRE, __HIP_MEMORY_SCOPE_AGENT);
        } while (__any(lane < 5 && v < g) && ++tries < (1 << 20));
      }
      __syncthreads();
      const u16* src = hx + (size_t)((dir * 2 + ((g - 1) & 1)) * B_) * 320;
      for (int i = tid; i < B_ * 320; i += 1024) {
        int bb = i / 320, kq = i % 320;
        h_lds[bb * 328 + kq] = src[i];
      }
      __syncthreads();
    }

    // recurrent GEMV tile via MFMA: D[b][u] = sum_k h[b,k] * Whh[n,k]
    {
      float4v acc = (float4v){0.f, 0.f, 0.f, 0.f};
      int m = lane & 15;
      int kbase = (lane >> 4) * 8;
      const u16* hl = h_lds + m * 328 + kbase;
#pragma unroll
      for (int kk = 0; kk < 10; ++kk) {
        short8 af = *(const short8*)(hl + kk * 32);
        acc = __builtin_amdgcn_mfma_f32_16x16x32_bf16(af, bfr[kk], acc, 0, 0, 0);
      }
      int col = lane & 15;
      int rb = (lane >> 4) * 4;
#pragma unroll
      for (int r = 0; r < 4; r++)
        smem[(gate * 16 + rb + r) * 65 + q * 16 + col] = acc[r];
    }
    __syncthreads();

    if (active) {
      float zi = smem[(0 * 16 + b) * 65 + u_loc] + z_in[0] + bias_r[0];
      float zf = smem[(1 * 16 + b) * 65 + u_loc] + z_in[1] + bias_r[1];
      float zg = smem[(2 * 16 + b) * 65 + u_loc] + z_in[2] + bias_r[2];
      float zo = smem[(3 * 16 + b) * 65 + u_loc] + z_in[3] + bias_r[3];
      float ig = sigmoid_f(zi);
      float fg = sigmoid_f(zf);
      float gg = tanh_f(zg);
      float og = sigmoid_f(zo);
      c_state = fg * c_state + ig * gg;
      float hval = og * tanh_f(c_state);
      hx[(size_t)((dir * 2 + (g & 1)) * B_ + b) * 320 + u_glob] = f2bf(hval);
      float rv = hval > 0.f ? hval : 0.f;
#pragma unroll
      for (int n = 0; n < 4; ++n) clsacc[n] += rv * wc[n];
    }
    __threadfence();
    __syncthreads();
    if (tid == 0)
      __hip_atomic_store(&myflags[w], g + 1, __ATOMIC_RELEASE, __HIP_MEMORY_SCOPE_AGENT);

    if (s_mod == S_ - 1) {
      __syncthreads();
#pragma unroll
      for (int n = 0; n < 4; ++n) smem[(b * 64 + u_loc) * 4 + n] = clsacc[n];
      __syncthreads();
      if (tid < B_ * NC_) {
        int bb = tid >> 2, n = tid & 3;
        float s = 0.f;
        for (int u = 0; u < 64; ++u) s += smem[(bb * 64 + u) * 4 + n];
        atomicAdd(&outp[(t * B_ + bb) * NC_ + n], s);
      }
    }
  }
  cst[wgid * 1024 + tid] = c_state;
}

// ---------------------------------------------------------------------------
extern "C" void kernel_launch(void* const* d_in, const int* in_sizes, int n_in,
                              void* d_out, int out_size, void* d_ws, size_t ws_size,
                              hipStream_t stream) {
  const float* seq = (const float*)d_in[1];
  const float* sp = (const float*)d_in[2];
  const float* ep = (const float*)d_in[3];
  const float* cp = (const float*)d_in[4];
  const float* bsp = (const float*)d_in[5];
  const float* bep = (const float*)d_in[6];
  const float* bcp = (const float*)d_in[7];
  const float* um = (const float*)d_in[8];
  const float* nm = (const float*)d_in[9];
  const float* am = (const float*)d_in[10];
  const float* wihf = (const float*)d_in[11];
  const float* whhf = (const float*)d_in[12];
  const float* bihf = (const float*)d_in[13];
  const float* bhhf = (const float*)d_in[14];
  const float* wihb = (const float*)d_in[15];
  const float* whhb = (const float*)d_in[16];
  const float* bihb = (const float*)d_in[17];
  const float* bhhb = (const float*)d_in[18];
  const float* wcls = (const float*)d_in[19];
  const float* bcls = (const float*)d_in[20];

  char* ws = (char*)d_ws;
  size_t off = 0;
  auto alloc = [&](size_t bytes) -> char* {
    char* p = ws + off;
    off += (bytes + 255) & ~(size_t)255;
    return p;
  };
  u16* S0 = (u16*)alloc((size_t)T_ * M_ * D_ * 2);
  u16* SA = (u16*)alloc((size_t)T_ * M_ * D_ * 2);
  u16* SB = (u16*)alloc((size_t)T_ * M_ * D_ * 2);
  u16* SA0 = (u16*)alloc((size_t)M_ * D_ * 2);
  u16* SB0 = (u16*)alloc((size_t)M_ * D_ * 2);
  u16* WCAT = (u16*)alloc((size_t)N2_ * K5_ * 2);
  u16* WHH = (u16*)alloc((size_t)2 * G4_ * 320 * 2);
  float* BIAS = (float*)alloc((size_t)2 * G4_ * 4);
  float* Z = (float*)alloc((size_t)M_ * N2_ * 4);       // single-t slot
  u16* HX = (u16*)alloc((size_t)2 * 2 * B_ * 320 * 2);
  int* FLAGS = (int*)alloc(16 * 4);
  float* CST = (float*)alloc((size_t)10 * 1024 * 4);

  if (off > ws_size) {
    fprintf(stderr, "[kernel] ws too small: need %zu, have %zu\n", off, ws_size);
    return;
  }

  hipLaunchKernelGGL(k_prep_s, dim3(T_ * M_ + M_), dim3(256), 0, stream,
                     seq, sp, ep, cp, bsp, bep, bcp, um, nm, am, S0, SA, SB, SA0, SB0);
  hipLaunchKernelGGL(k_prep_w, dim3(N2_ + 2 * G4_ + 1), dim3(256), 0, stream,
                     wihf, wihb, whhf, whhb, bihf, bhhf, bihb, bhhb, bcls,
                     WCAT, WHH, BIAS, (float*)d_out, FLAGS, HX);
  for (int t = 0; t < T_; ++t) {
    hipLaunchKernelGGL(k_gemm, dim3(25, 19, 1), dim3(256), 0, stream,
                       S0, SA, SB, SA0, SB0, WCAT, Z, t);
    hipLaunchKernelGGL(k_lstm, dim3(10), dim3(1024), 0, stream,
                       Z, WHH, BIAS, wcls, HX, FLAGS, (float*)d_out, CST, t);
  }
}

// Round 3
// 8246.479 us; speedup vs baseline: 2.5251x; 2.5251x over previous
//
#include <hip/hip_runtime.h>
#include <stdint.h>
#include <stdio.h>

#define T_ 10
#define B_ 16
#define S_ 200
#define D_ 768
#define H_ 300
#define NC_ 4
#define M_ (S_ * B_)   /* 3200 rows per t */
#define K5_ (5 * D_)   /* 3840 */
#define N2_ 2400       /* 2 dirs * 4H */
#define G4_ 1200       /* 4H */
#define HXW_SLOT 4864  /* u32 words per parity slot (4800 = 300u x 16b used) */
#define HLDS_STRIDE 336

typedef unsigned short u16;
typedef unsigned int u32;
typedef __attribute__((ext_vector_type(8))) short short8;
typedef __attribute__((ext_vector_type(4))) float float4v;

static __device__ __forceinline__ u16 f2bf(float x) {
  union { float f; u32 u; } v; v.f = x;
  u32 u = v.u;
  u32 r = (u + 0x7FFFu + ((u >> 16) & 1u)) >> 16;
  return (u16)r;
}

static __device__ __forceinline__ void async16(const void* g, void* l) {
  __builtin_amdgcn_global_load_lds((const __attribute__((address_space(1))) u32*)g,
                                   (__attribute__((address_space(3))) u32*)l, 16, 0, 0);
}

static __device__ __forceinline__ float sigmoid_f(float x) {
  return 1.f / (1.f + __expf(-x));
}
static __device__ __forceinline__ float tanh_f(float x) {
  float e = __expf(2.f * x);
  return 1.f - 2.f / (e + 1.f);   // safe at e=inf -> 1, e=0 -> -1
}

// ---------------------------------------------------------------------------
// K0a: build S0 = bf16(seq), SA = a .* seq, SB = b .* seq  (layout [t][s][b][768])
//      plus before-state SA0/SB0 (t=0 before-state weights on seq[0])
// ---------------------------------------------------------------------------
__global__ void k_prep_s(const float* __restrict__ seq,
                         const float* __restrict__ sp, const float* __restrict__ ep,
                         const float* __restrict__ cp,
                         const float* __restrict__ bsp, const float* __restrict__ bep,
                         const float* __restrict__ bcp,
                         const float* __restrict__ um, const float* __restrict__ nm,
                         const float* __restrict__ am,
                         u16* __restrict__ s0, u16* __restrict__ sa, u16* __restrict__ sb,
                         u16* __restrict__ sa0, u16* __restrict__ sb0) {
  int bid = blockIdx.x;
  int tid = threadIdx.x;  // 256
  if (bid < T_ * M_) {
    int t = bid / M_;
    int r = bid % M_;
    int s = r >> 4, b = r & 15;
    float c0 = cp[(t * B_ + b) * NC_ + 0];
    float c1 = cp[(t * B_ + b) * NC_ + 1];
    float c2 = cp[(t * B_ + b) * NC_ + 2];
    int mi = (b * T_ + t) * S_ + s;
    float w = am[mi] * c0 + um[mi] * c1 + nm[mi] * c2;
    float aw = sp[(t * B_ + b) * S_ + s] * w;
    float bw = ep[(t * B_ + b) * S_ + s] * w;
    const float* x = seq + ((size_t)(t * B_ + b) * S_ + s) * D_;
    size_t ob = (size_t)bid * D_;
    for (int d = tid; d < D_; d += 256) {
      float xv = x[d];
      s0[ob + d] = f2bf(xv);
      sa[ob + d] = f2bf(aw * xv);
      sb[ob + d] = f2bf(bw * xv);
    }
  } else {
    int r = bid - T_ * M_;
    int s = r >> 4, b = r & 15;
    float c0 = bcp[b * NC_ + 0], c1 = bcp[b * NC_ + 1], c2 = bcp[b * NC_ + 2];
    int mi = (b * T_ + 0) * S_ + s;
    float w = am[mi] * c0 + um[mi] * c1 + nm[mi] * c2;
    float aw = bsp[b * S_ + s] * w;
    float bw = bep[b * S_ + s] * w;
    const float* x = seq + ((size_t)b * S_ + s) * D_;
    size_t ob = (size_t)r * D_;
    for (int d = tid; d < D_; d += 256) {
      float xv = x[d];
      sa0[ob + d] = f2bf(aw * xv);
      sb0[ob + d] = f2bf(bw * xv);
    }
  }
}

// ---------------------------------------------------------------------------
// K0b: Wcat bf16 [2400][3840], Whh padded bf16 [2][1200][320], bias=bih+bhh,
//      d_out seeded with bcls, hxw (tagged h exchange buffer) zeroed
// ---------------------------------------------------------------------------
__global__ void k_prep_w(const float* __restrict__ wf, const float* __restrict__ wb,
                         const float* __restrict__ whf, const float* __restrict__ whb,
                         const float* __restrict__ bihf, const float* __restrict__ bhhf,
                         const float* __restrict__ bihb, const float* __restrict__ bhhb,
                         const float* __restrict__ bcls,
                         u16* __restrict__ wcat, u16* __restrict__ whh,
                         float* __restrict__ bias, float* __restrict__ outp,
                         u32* __restrict__ hxw) {
  int bid = blockIdx.x, tid = threadIdx.x;
  if (bid < N2_) {
    const float* src = bid < G4_ ? wf + (size_t)bid * K5_ : wb + (size_t)(bid - G4_) * K5_;
    u16* dst = wcat + (size_t)bid * K5_;
    for (int k = tid; k < K5_; k += 256) dst[k] = f2bf(src[k]);
  } else if (bid < N2_ + 2 * G4_) {
    int r = bid - N2_;
    int dir = r / G4_, n = r % G4_;
    const float* src = (dir ? whb : whf) + (size_t)n * H_;
    u16* dst = whh + (size_t)(dir * G4_ + n) * 320;
    for (int k = tid; k < 320; k += 256) dst[k] = (k < H_) ? f2bf(src[k]) : (u16)0;
  } else {
    for (int i = tid; i < 2 * G4_; i += 256) {
      int dir = i / G4_, n = i % G4_;
      bias[i] = dir ? (bihb[n] + bhhb[n]) : (bihf[n] + bhhf[n]);
    }
    for (int i = tid; i < T_ * B_ * NC_; i += 256) outp[i] = bcls[i & 3];
    for (int i = tid; i < 2 * 2 * HXW_SLOT; i += 256) hxw[i] = 0;  // tag 0 = invalid
  }
}

// ---------------------------------------------------------------------------
// K1: z[s][b][2400] = rnn_in(t) @ [Wih_f;Wih_b]^T  (bf16 MFMA, fp32 out)
// ---------------------------------------------------------------------------
__global__ __launch_bounds__(256, 3) void k_gemm(
    const u16* __restrict__ s0, const u16* __restrict__ sa, const u16* __restrict__ sb,
    const u16* __restrict__ sa0, const u16* __restrict__ sb0,
    const u16* __restrict__ wcat, float* __restrict__ z, int t) {
  __shared__ __align__(16) u16 As[128 * 32];
  __shared__ __align__(16) u16 Bs[128 * 32];
  int m0 = blockIdx.x * 128;
  int n0 = blockIdx.y * 128;
  int tid = threadIdx.x;
  int lane = tid & 63, wv = tid >> 6;
  int wm = wv & 1, wn = wv >> 1;

  const u16* ap[5];
  ap[0] = s0 + (size_t)t * M_ * D_;
  ap[1] = sa + (size_t)t * M_ * D_;
  ap[2] = sb + (size_t)t * M_ * D_;
  ap[3] = t ? sa + (size_t)(t - 1) * M_ * D_ : sa0;
  ap[4] = t ? sb + (size_t)(t - 1) * M_ * D_ : sb0;

  float4v acc[4][4];
#pragma unroll
  for (int i = 0; i < 4; i++)
#pragma unroll
    for (int j = 0; j < 4; j++) acc[i][j] = (float4v){0.f, 0.f, 0.f, 0.f};

  int rowA = tid >> 2;   // 0..63
  int seg = tid & 3;

  for (int which = 0; which < 5; ++which) {
    const u16* ab = which == 0 ? ap[0] : which == 1 ? ap[1] : which == 2 ? ap[2]
                    : which == 3 ? ap[3] : ap[4];
    for (int kk = 0; kk < 24; ++kk) {
      int kof = kk * 32;
#pragma unroll
      for (int j = 0; j < 2; ++j) {
        int row = j * 64 + rowA;
        const u16* g = ab + (size_t)(m0 + row) * D_ + kof + seg * 8;
        async16(g, As + wv * 512 + j * 2048);
      }
#pragma unroll
      for (int j = 0; j < 2; ++j) {
        int row = j * 64 + rowA;
        int nr = n0 + row;
        if (nr > N2_ - 1) nr = N2_ - 1;
        const u16* g = wcat + (size_t)nr * K5_ + which * D_ + kof + seg * 8;
        async16(g, Bs + wv * 512 + j * 2048);
      }
      __syncthreads();
      short8 af[4], bf[4];
#pragma unroll
      for (int i = 0; i < 4; i++) {
        af[i] = *(const short8*)&As[(wm * 64 + i * 16 + (lane & 15)) * 32 + (lane >> 4) * 8];
        bf[i] = *(const short8*)&Bs[(wn * 64 + i * 16 + (lane & 15)) * 32 + (lane >> 4) * 8];
      }
#pragma unroll
      for (int i = 0; i < 4; i++)
#pragma unroll
        for (int j = 0; j < 4; j++)
          acc[i][j] = __builtin_amdgcn_mfma_f32_16x16x32_bf16(af[i], bf[j], acc[i][j], 0, 0, 0);
      __syncthreads();
    }
  }
#pragma unroll
  for (int i = 0; i < 4; i++) {
    int m = m0 + wm * 64 + i * 16 + (lane >> 4) * 4;
#pragma unroll
    for (int j = 0; j < 4; j++) {
      int n = n0 + wn * 64 + j * 16 + (lane & 15);
      if (n < N2_) {
#pragma unroll
        for (int r = 0; r < 4; r++) z[(size_t)(m + r) * N2_ + n] = acc[i][j][r];
      }
    }
  }
}

// ---------------------------------------------------------------------------
// K2: persistent bidirectional LSTM + fused classifier, one t per launch.
// Grid = 10 blocks x 1024 thr -> (dir = b/5, w = b%5). Each wg owns u-slice
// [64w, 64w+64) of H; Whh slice lives in registers as MFMA B-fragments.
// h exchange: self-validating tagged words ((g)<<16 | bf16(h)) in a parity
// double-buffer, relaxed agent-scope atomics only — NO fences, NO flags.
// Safety: slot p is overwritten with tag g+2 only after every wg consumed
// tag g (publication of g+1 certifies consumption of g), so a poller of tag
// g can only ever see tag <= g in that slot until it consumes it.
// ---------------------------------------------------------------------------
__global__ __launch_bounds__(1024, 4) void k_lstm(
    const float* __restrict__ z, const u16* __restrict__ whh,
    const float* __restrict__ bias, const float* __restrict__ wcls,
    u32* __restrict__ hxw, float* __restrict__ outp,
    float* __restrict__ cst, int t) {
  __shared__ __align__(16) u16 h_lds[16 * HLDS_STRIDE];
  __shared__ __align__(16) float smem[4160];  // zbuf [4][16][65] / cls-reduce [16][64][4]

  int wgid = blockIdx.x;
  int dir = wgid / 5;
  int w = wgid % 5;
  int tid = threadIdx.x;
  int lane = tid & 63, wv = tid >> 6;
  int gate = wv >> 2, q = wv & 3;

  // persistent Whh B-fragments: wave covers cols n = gate*300 + w*64 + q*16 + (lane&15)
  short8 bfr[10];
  {
    int col = lane & 15;
    int u = w * 64 + q * 16 + col;
    int krow = (lane >> 4) * 8;
    if (u < H_) {
      const u16* base = whh + (size_t)(dir * G4_ + gate * H_ + u) * 320 + krow;
#pragma unroll
      for (int kk = 0; kk < 10; ++kk) bfr[kk] = *(const short8*)(base + kk * 32);
    } else {
#pragma unroll
      for (int kk = 0; kk < 10; ++kk) bfr[kk] = (short8){0, 0, 0, 0, 0, 0, 0, 0};
    }
  }

  // thread view for gate/classifier phase
  int b = tid >> 6;
  int u_loc = tid & 63;
  int u_glob = w * 64 + u_loc;
  bool active = u_glob < H_;
  float bias_r[4];
#pragma unroll
  for (int g = 0; g < 4; ++g)
    bias_r[g] = active ? bias[dir * G4_ + g * H_ + u_glob] : 0.f;

  float c_state = t > 0 ? cst[wgid * 1024 + tid] : 0.f;
  float clsacc[4] = {0.f, 0.f, 0.f, 0.f};

  for (int i = tid; i < 16 * HLDS_STRIDE; i += 1024) h_lds[i] = 0;
  __syncthreads();

  u32* hx_base = hxw + dir * 2 * HXW_SLOT;

  // poll set: words i = tid + j*1024 (< 4800), skipping our own u-slice
  // (we write our own h straight to LDS at publish time)
  u32 pend0 = 0;
#pragma unroll
  for (int j = 0; j < 5; ++j) {
    int i = tid + j * 1024;
    if (i < 4800) {
      int u = i >> 4;
      if (!(u >= w * 64 && u < (w + 1) * 64)) pend0 |= 1u << j;
    }
  }

  for (int s_mod = 0; s_mod < S_; ++s_mod) {
    int g = t * S_ + s_mod;
    int s_in = dir ? (S_ - 1 - s_mod) : s_mod;

    // prefetch (independent of sync): z input row + Wcls column
    float z_in[4] = {0.f, 0.f, 0.f, 0.f}, wc[4] = {0.f, 0.f, 0.f, 0.f};
    if (active) {
      const float* zr = z + (size_t)(s_in * B_ + b) * N2_ + dir * G4_;
      int ycol = s_in * 600 + dir * H_ + u_glob;
#pragma unroll
      for (int gg = 0; gg < 4; ++gg) z_in[gg] = zr[gg * H_ + u_glob];
#pragma unroll
      for (int n = 0; n < 4; ++n) wc[n] = wcls[(size_t)n * (S_ * 600) + ycol];
    }

    if (g > 0) {
      const u32* src = hx_base + (g & 1) * HXW_SLOT;
      u32 pend = pend0;
      int tries = 0;
      while (pend && tries < (1 << 20)) {
        u32 got[5];
#pragma unroll
        for (int j = 0; j < 5; ++j)
          if (pend & (1u << j))
            got[j] = __hip_atomic_load(&src[tid + j * 1024], __ATOMIC_RELAXED,
                                       __HIP_MEMORY_SCOPE_AGENT);
#pragma unroll
        for (int j = 0; j < 5; ++j)
          if ((pend & (1u << j)) && (got[j] >> 16) >= (u32)g) {
            int i = tid + j * 1024;
            h_lds[(i & 15) * HLDS_STRIDE + (i >> 4)] = (u16)(got[j] & 0xffffu);
            pend &= ~(1u << j);
          }
        ++tries;
      }
      __syncthreads();
    }

    // recurrent GEMV tile via MFMA: D[b][u] = sum_k h[b,k] * Whh[n,k]
    {
      float4v acc = (float4v){0.f, 0.f, 0.f, 0.f};
      int m = lane & 15;
      int kbase = (lane >> 4) * 8;
      const u16* hl = h_lds + m * HLDS_STRIDE + kbase;
#pragma unroll
      for (int kk = 0; kk < 10; ++kk) {
        short8 af = *(const short8*)(hl + kk * 32);
        acc = __builtin_amdgcn_mfma_f32_16x16x32_bf16(af, bfr[kk], acc, 0, 0, 0);
      }
      int col = lane & 15;
      int rb = (lane >> 4) * 4;
#pragma unroll
      for (int r = 0; r < 4; r++)
        smem[(gate * 16 + rb + r) * 65 + q * 16 + col] = acc[r];
    }
    __syncthreads();

    if (active) {
      float zi = smem[(0 * 16 + b) * 65 + u_loc] + z_in[0] + bias_r[0];
      float zf = smem[(1 * 16 + b) * 65 + u_loc] + z_in[1] + bias_r[1];
      float zg = smem[(2 * 16 + b) * 65 + u_loc] + z_in[2] + bias_r[2];
      float zo = smem[(3 * 16 + b) * 65 + u_loc] + z_in[3] + bias_r[3];
      float ig = sigmoid_f(zi);
      float fg = sigmoid_f(zf);
      float gg = tanh_f(zg);
      float og = sigmoid_f(zo);
      c_state = fg * c_state + ig * gg;
      float hval = og * tanh_f(c_state);
      u16 hb = f2bf(hval);
      // publish ASAP: tagged word, relaxed, no fence
      u32 wrd = ((u32)(g + 1) << 16) | (u32)hb;
      __hip_atomic_store(&hx_base[((g + 1) & 1) * HXW_SLOT + u_glob * 16 + b], wrd,
                         __ATOMIC_RELAXED, __HIP_MEMORY_SCOPE_AGENT);
      // own slice goes straight to LDS for the next step
      h_lds[b * HLDS_STRIDE + u_glob] = hb;
      float rv = hval > 0.f ? hval : 0.f;
#pragma unroll
      for (int n = 0; n < 4; ++n) clsacc[n] += rv * wc[n];
    }

    if (s_mod == S_ - 1) {
      __syncthreads();
#pragma unroll
      for (int n = 0; n < 4; ++n) smem[(b * 64 + u_loc) * 4 + n] = clsacc[n];
      __syncthreads();
      if (tid < B_ * NC_) {
        int bb = tid >> 2, n = tid & 3;
        float s = 0.f;
        for (int u = 0; u < 64; ++u) s += smem[(bb * 64 + u) * 4 + n];
        atomicAdd(&outp[(t * B_ + bb) * NC_ + n], s);
      }
    }
  }
  cst[wgid * 1024 + tid] = c_state;
}

// ---------------------------------------------------------------------------
extern "C" void kernel_launch(void* const* d_in, const int* in_sizes, int n_in,
                              void* d_out, int out_size, void* d_ws, size_t ws_size,
                              hipStream_t stream) {
  const float* seq = (const float*)d_in[1];
  const float* sp = (const float*)d_in[2];
  const float* ep = (const float*)d_in[3];
  const float* cp = (const float*)d_in[4];
  const float* bsp = (const float*)d_in[5];
  const float* bep = (const float*)d_in[6];
  const float* bcp = (const float*)d_in[7];
  const float* um = (const float*)d_in[8];
  const float* nm = (const float*)d_in[9];
  const float* am = (const float*)d_in[10];
  const float* wihf = (const float*)d_in[11];
  const float* whhf = (const float*)d_in[12];
  const float* bihf = (const float*)d_in[13];
  const float* bhhf = (const float*)d_in[14];
  const float* wihb = (const float*)d_in[15];
  const float* whhb = (const float*)d_in[16];
  const float* bihb = (const float*)d_in[17];
  const float* bhhb = (const float*)d_in[18];
  const float* wcls = (const float*)d_in[19];
  const float* bcls = (const float*)d_in[20];

  char* ws = (char*)d_ws;
  size_t off = 0;
  auto alloc = [&](size_t bytes) -> char* {
    char* p = ws + off;
    off += (bytes + 255) & ~(size_t)255;
    return p;
  };
  u16* S0 = (u16*)alloc((size_t)T_ * M_ * D_ * 2);
  u16* SA = (u16*)alloc((size_t)T_ * M_ * D_ * 2);
  u16* SB = (u16*)alloc((size_t)T_ * M_ * D_ * 2);
  u16* SA0 = (u16*)alloc((size_t)M_ * D_ * 2);
  u16* SB0 = (u16*)alloc((size_t)M_ * D_ * 2);
  u16* WCAT = (u16*)alloc((size_t)N2_ * K5_ * 2);
  u16* WHH = (u16*)alloc((size_t)2 * G4_ * 320 * 2);
  float* BIAS = (float*)alloc((size_t)2 * G4_ * 4);
  float* Z = (float*)alloc((size_t)M_ * N2_ * 4);       // single-t slot
  u32* HXW = (u32*)alloc((size_t)2 * 2 * HXW_SLOT * 4); // tagged h, 2 dirs x 2 slots
  float* CST = (float*)alloc((size_t)10 * 1024 * 4);

  if (off > ws_size) {
    fprintf(stderr, "[kernel] ws too small: need %zu, have %zu\n", off, ws_size);
    return;
  }

  hipLaunchKernelGGL(k_prep_s, dim3(T_ * M_ + M_), dim3(256), 0, stream,
                     seq, sp, ep, cp, bsp, bep, bcp, um, nm, am, S0, SA, SB, SA0, SB0);
  hipLaunchKernelGGL(k_prep_w, dim3(N2_ + 2 * G4_ + 1), dim3(256), 0, stream,
                     wihf, wihb, whhf, whhb, bihf, bhhf, bihb, bhhb, bcls,
                     WCAT, WHH, BIAS, (float*)d_out, HXW);
  for (int t = 0; t < T_; ++t) {
    hipLaunchKernelGGL(k_gemm, dim3(25, 19, 1), dim3(256), 0, stream,
                       S0, SA, SB, SA0, SB0, WCAT, Z, t);
    hipLaunchKernelGGL(k_lstm, dim3(10), dim3(1024), 0, stream,
                       Z, WHH, BIAS, wcls, HXW, (float*)d_out, CST, t);
  }
}